// Round 6
// baseline (296.058 us; speedup 1.0000x reference)
//
#include <hip/hip_runtime.h>
#include <math.h>

#define NHID 1024
#define NPC  225
#define NCLS 224
#define BATCH 1024
#define N_BOTB 352              // bottom blocks FIRST: bids 0..351
#define N_TOPB 128              // top blocks: bids 352..479

// ws float-offsets
#define WS_PT 0                 // float pt[1024]
#define WS_PB 1024              // float pb[1024]

// ---------------------------------------------------------------------------
// Shared panel routine: 8 staged samples vs one [NHID x ncols] weight panel,
// per-sample softmax over ncols, write the picked probability.
// 512 threads = 8 waves; wave w covers d-rows [128w, 128w+128).
// Scalar coalesced weight loads (64 consecutive cols per instruction).
// ---------------------------------------------------------------------------
template<bool NT>
__device__ __forceinline__ void panel8(const float* __restrict__ X,
                                       const int* __restrict__ labels,
                                       float* sm, const int* slot,
                                       const float* __restrict__ W, int ncols,
                                       const float* __restrict__ bias,
                                       int nt, bool use_mod,
                                       float* __restrict__ outp)
{
    const int tid  = threadIdx.x;
    const int wave = tid >> 6;
    const int lane = tid & 63;
    const int j8   = tid & 7;

    // stage nt rows of X transposed ([d][j], row stride 12)
    const int sid = (j8 < nt) ? slot[j8] : -1;
    for (int idx = tid; idx < 2048; idx += 512) {
        const int d4 = idx >> 3;
        float4 v = make_float4(0.f, 0.f, 0.f, 0.f);
        if (sid >= 0) v = ((const float4*)&X[(size_t)sid * NHID])[d4];
        float* p = &sm[48 * d4 + j8];
        p[0] = v.x; p[12] = v.y; p[24] = v.z; p[36] = v.w;
    }
    __syncthreads();

    float acc[8][4];
#pragma unroll
    for (int j = 0; j < 8; ++j)
#pragma unroll
        for (int k = 0; k < 4; ++k) acc[j][k] = 0.f;

    const int c0 = lane, c1 = lane + 64, c2 = lane + 128, c3 = lane + 192;
    const bool m3 = (c3 < ncols);
    const int d0 = wave * 128;
    const float* Wr = W + (size_t)d0 * ncols;

    auto ldrow = [&](int r, float* o) {
        const float* p = Wr + (size_t)r * ncols;
        if (NT) {
            o[0] = __builtin_nontemporal_load(p + c0);
            o[1] = __builtin_nontemporal_load(p + c1);
            o[2] = __builtin_nontemporal_load(p + c2);
            o[3] = m3 ? __builtin_nontemporal_load(p + c3) : 0.f;
        } else {
            o[0] = p[c0]; o[1] = p[c1]; o[2] = p[c2];
            o[3] = m3 ? p[c3] : 0.f;
        }
    };
    float wbuf[4][4];
    ldrow(0, wbuf[0]); ldrow(1, wbuf[1]); ldrow(2, wbuf[2]); ldrow(3, wbuf[3]);

#pragma unroll 4
    for (int dd = 0; dd < 128; ++dd) {
        const int sl = dd & 3;
        const float cw0 = wbuf[sl][0], cw1 = wbuf[sl][1],
                    cw2 = wbuf[sl][2], cw3 = wbuf[sl][3];
        ldrow(min(dd + 4, 127), wbuf[sl]);   // clamped tail re-read (cache hit)
        const float4 a = *(const float4*)&sm[(d0 + dd) * 12 + 0];
        const float4 b = *(const float4*)&sm[(d0 + dd) * 12 + 4];
        const float xi[8] = {a.x, a.y, a.z, a.w, b.x, b.y, b.z, b.w};
#pragma unroll
        for (int j = 0; j < 8; ++j) {
            acc[j][0] = fmaf(xi[j], cw0, acc[j][0]);
            acc[j][1] = fmaf(xi[j], cw1, acc[j][1]);
            acc[j][2] = fmaf(xi[j], cw2, acc[j][2]);
            acc[j][3] = fmaf(xi[j], cw3, acc[j][3]);
        }
    }
    __syncthreads();   // all waves done reading staging

    float* red = sm;   // red[(w*8 + j)*232 + c]
#pragma unroll
    for (int j = 0; j < 8; ++j)
#pragma unroll
        for (int k = 0; k < 4; ++k) {
            const int c = lane + 64 * k;
            if (c < ncols) red[(wave * 8 + j) * 232 + c] = acc[j][k];
        }
    __syncthreads();

    if (wave < nt) {
        const int j = wave;
        const int s = slot[j];
        float v0, v1, v2, v3;
        {
            float vv[4];
#pragma unroll
            for (int k = 0; k < 4; ++k) {
                const int c = lane + 64 * k;
                if (c < ncols) {
                    float t = bias[c];
#pragma unroll
                    for (int g = 0; g < 8; ++g) t += red[(g * 8 + j) * 232 + c];
                    vv[k] = t;
                } else vv[k] = -INFINITY;
            }
            v0 = vv[0]; v1 = vv[1]; v2 = vv[2]; v3 = vv[3];
        }
        float m = fmaxf(fmaxf(v0, v1), fmaxf(v2, v3));
        for (int o = 32; o > 0; o >>= 1) m = fmaxf(m, __shfl_xor(m, o));
        float e = expf(v0 - m) + expf(v1 - m) + expf(v2 - m) + expf(v3 - m);
        for (int o = 32; o > 0; o >>= 1) e += __shfl_xor(e, o);
        const int lab  = labels[s];
        const int pick = use_mod ? (lab % NPC) : (lab / NPC);
        if (lane == (pick & 63)) {
            const int kk = pick >> 6;
            const float vs = kk == 0 ? v0 : kk == 1 ? v1 : kk == 2 ? v2 : v3;
            outp[s] = expf(vs - m) / e;
        }
    }
}

// ---------------------------------------------------------------------------
// Fused kernel: 480 blocks x 512 threads (8 waves), 61.5 KB LDS, <=128 VGPR
// -> 2 blocks/CU co-resident; all 480 blocks resident from t=0.
// Bottom blocks DISPATCH FIRST (bids 0..351) so the 203 MB Wb stream starts
// immediately; top blocks (352..479) land in second CU slots and their VALU
// work hides under the bottom blocks' vmcnt stalls.
// Grouping critical path cut to 3 barriers: LDS histogram + single-wave
// __shfl_up scan of the 256 per-class item counts (4 classes per lane).
// ---------------------------------------------------------------------------
__global__ __launch_bounds__(512, 4) void k_fused(const float* __restrict__ X,
                                                  const int* __restrict__ labels,
                                                  const float* __restrict__ Wt,
                                                  const float* __restrict__ bt,
                                                  const float* __restrict__ Wb,
                                                  const float* __restrict__ bb,
                                                  float* __restrict__ ws)
{
    __shared__ __align__(16) float sm[14848]; // staging [256][48] / red[64][232]
    __shared__ int cnt_[256];
    __shared__ int iscan_[256];
    __shared__ int slot[8];
    __shared__ int wtA[8], wtB[8];

    const int tid  = threadIdx.x;
    const int wave = tid >> 6;
    const int lane = tid & 63;
    const int bid  = blockIdx.x;

    if (bid >= N_BOTB) {
        // ----------------------------- top -----------------------------
        if (tid < 8) slot[tid] = (bid - N_BOTB) * 8 + tid;
        __syncthreads();
        panel8<false>(X, labels, sm, slot, Wt, NCLS, bt, 8, false, ws + WS_PT);
        return;
    }

    // ---------------------------- bottom ----------------------------
    // self-grouping, 3-barrier critical path
    if (tid < 256) cnt_[tid] = 0;
    __syncthreads();
    const int la = labels[tid] / NPC;          // samples tid and tid+512
    const int lb = labels[tid + 512] / NPC;
    atomicAdd(&cnt_[la], 1);
    atomicAdd(&cnt_[lb], 1);
    __syncthreads();
    if (wave == 0) {                           // wave-0 scan: 4 classes/lane
        const int b4 = 4 * lane;
        const int e0 = (b4 + 0 < NCLS) ? ((cnt_[b4 + 0] + 7) >> 3) : 0;
        const int e1 = (b4 + 1 < NCLS) ? ((cnt_[b4 + 1] + 7) >> 3) : 0;
        const int e2 = (b4 + 2 < NCLS) ? ((cnt_[b4 + 2] + 7) >> 3) : 0;
        const int e3 = (b4 + 3 < NCLS) ? ((cnt_[b4 + 3] + 7) >> 3) : 0;
        const int s0 = e0, s1 = s0 + e1, s2 = s1 + e2, s3 = s2 + e3;
        int run = s3;
        for (int o = 1; o < 64; o <<= 1) {     // inclusive wave scan
            const int t = __shfl_up(run, o);
            if (lane >= o) run += t;
        }
        const int base = run - s3;
        iscan_[b4 + 0] = base + s0;
        iscan_[b4 + 1] = base + s1;
        iscan_[b4 + 2] = base + s2;
        iscan_[b4 + 3] = base + s3;
    }
    __syncthreads();
    const int item = bid;
    if (item >= iscan_[255]) return;           // beyond nitems: uniform exit

    // locate class: first cls with iscan_[cls] > item (LDS broadcast reads)
    int lo = 0, hi = NCLS - 1;
    while (lo < hi) {
        const int mid = (lo + hi) >> 1;
        if (iscan_[mid] > item) hi = mid; else lo = mid + 1;
    }
    const int cls    = lo;
    const int ibase  = (cls == 0) ? 0 : iscan_[cls - 1];
    const int within = item - ibase;
    const int nt     = min(8, cnt_[cls] - 8 * within);

    // deterministic compaction: (half, wave, lane) order == sample order
    const bool fA = (la == cls), fB = (lb == cls);
    const unsigned long long mA = __ballot(fA);
    const unsigned long long mB = __ballot(fB);
    if (lane == 0) { wtA[wave] = __popcll(mA); wtB[wave] = __popcll(mB); }
    __syncthreads();
    int preA = 0, preB = 0, totA = 0;
#pragma unroll
    for (int w = 0; w < 8; ++w) {
        totA += wtA[w];
        if (w < wave) { preA += wtA[w]; preB += wtB[w]; }
    }
    preB += totA;
    if (fA) {
        const int r = preA + (int)__popcll(mA & ((1ull << lane) - 1)) - 8 * within;
        if (r >= 0 && r < 8) slot[r] = tid;
    }
    if (fB) {
        const int r = preB + (int)__popcll(mB & ((1ull << lane) - 1)) - 8 * within;
        if (r >= 0 && r < 8) slot[r] = tid + 512;
    }
    __syncthreads();

    panel8<true>(X, labels, sm, slot,
                 Wb + (size_t)cls * (NHID * NPC), NPC,
                 bb + (size_t)cls * NPC, nt, true, ws + WS_PB);
}

// ---------------------------------------------------------------------------
// Finalize: out[s] = pt[s] * pb[s]
// ---------------------------------------------------------------------------
__global__ void k_mul(const float* __restrict__ ws, float* __restrict__ out)
{
    const int i = blockIdx.x * 256 + threadIdx.x;
    if (i < BATCH) out[i] = ws[WS_PT + i] * ws[WS_PB + i];
}

// ---------------------------------------------------------------------------
extern "C" void kernel_launch(void* const* d_in, const int* in_sizes, int n_in,
                              void* d_out, int out_size, void* d_ws, size_t ws_size,
                              hipStream_t stream)
{
    const float* X      = (const float*)d_in[0];
    const int*   labels = (const int*)  d_in[1];
    const float* Wt     = (const float*)d_in[2];
    const float* bt     = (const float*)d_in[3];
    const float* Wb     = (const float*)d_in[4];
    const float* bb     = (const float*)d_in[5];

    hipLaunchKernelGGL(k_fused, dim3(N_BOTB + N_TOPB), dim3(512), 0, stream,
                       X, labels, Wt, bt, Wb, bb, (float*)d_ws);
    hipLaunchKernelGGL(k_mul, dim3(BATCH / 256), dim3(256), 0, stream,
                       (const float*)d_ws, (float*)d_out);
}